// Round 3
// baseline (2112.555 us; speedup 1.0000x reference)
//
#include <hip/hip_runtime.h>
#include <hip/hip_bf16.h>
#include <stdint.h>

typedef __attribute__((ext_vector_type(8))) short short8;
typedef __attribute__((ext_vector_type(4))) float f32x4;
typedef unsigned short u16;

// ---------------- workspace layout (bytes) ----------------
#define OFF_PSUM 0ULL                      // 1e6*64*4 = 256,000,000
#define OFF_CNT  256000000ULL              // 1e6*4
#define OFF_EBF  260000000ULL              // 1e6*64*2 = 128,000,000
#define OFF_WT1  388000000ULL              // W1^T: 128*160*2 = 40960
#define OFF_WT2  (OFF_WT1 + 40960ULL)      // W2'^T: 128*128*2 = 32768
#define OFF_WT3  (OFF_WT2 + 32768ULL)      // W3'^T: 64*128*2 = 16384
#define OFF_S2   (OFF_WT3 + 16384ULL)      // 128*4
#define OFF_C2   (OFF_S2 + 512ULL)         // 128*4
#define OFF_S3   (OFF_C2 + 512ULL)         // 64*4
#define OFF_T3   (OFF_S3 + 256ULL)         // 64*4

// ---------------- LDS layout (bytes) ----------------
// X: [128 triplets][320B] (swizzled); M later aliases [0..32768) as [128][256B]
// H: [128 triplets][256B] swizzled
#define LDS_X   0
#define LDS_H   40960
#define LDS_P1S 73728   // float[128][2]
#define LDS_P1Q 74752
#define LDS_P2S 75776
#define LDS_P2Q 76800
#define LDS_EIJ 77824   // int[128]
#define LDS_EKJ 78336
#define LDS_TOTAL 78848

__device__ __forceinline__ u16 f2bf(float f) {
  union { float f; uint32_t u; } c; c.f = f;
  uint32_t u = c.u;
  return (u16)((u + 0x7FFFu + ((u >> 16) & 1u)) >> 16);  // RNE
}
__device__ __forceinline__ uint32_t pkbf(float lo, float hi) {
  float2 t; t.x = lo; t.y = hi;
  __hip_bfloat162 h = __float22bfloat162_rn(t);
  uint32_t u; __builtin_memcpy(&u, &h, 4);
  return u;
}
__device__ __forceinline__ float silu(float y) {
  return y * __builtin_amdgcn_rcpf(1.0f + __expf(-y));
}

#define MFMA16(a, b, c) __builtin_amdgcn_mfma_f32_16x16x32_bf16((a), (b), (c), 0, 0, 0)

// ---------------- prep kernels ----------------

__global__ __launch_bounds__(256) void k_conv_edge(const float* __restrict__ ef,
                                                   u16* __restrict__ ebf) {
  int i = blockIdx.x * 256 + threadIdx.x;  // < 16,000,000
  float4 v = ((const float4*)ef)[i];
  ushort4 o;
  o.x = f2bf(v.x); o.y = f2bf(v.y); o.z = f2bf(v.z); o.w = f2bf(v.w);
  ((ushort4*)ebf)[i] = o;
}

// transposed packed weights, row-major [n][k]:
// wt1[n*160+k] = W1[k,n] (k<132, else 0); wt2[n*128+k] = g1[k]*W2[k,n];
// wt3[n*128+k] = g2[k]*W3[k,n] (n<64)
__global__ __launch_bounds__(256) void k_pack_w(const float* __restrict__ W1,
                                                const float* __restrict__ W2,
                                                const float* __restrict__ W3,
                                                const float* __restrict__ g1,
                                                const float* __restrict__ g2,
                                                u16* __restrict__ wt1,
                                                u16* __restrict__ wt2,
                                                u16* __restrict__ wt3) {
  int i = blockIdx.x * 256 + threadIdx.x;  // < 45056
  if (i < 20480) {
    int n = i / 160, k = i - n * 160;
    wt1[i] = (k < 132) ? f2bf(W1[k * 128 + n]) : (u16)0;
  } else if (i < 36864) {
    int i2 = i - 20480;
    int n = i2 >> 7, k = i2 & 127;
    wt2[i2] = f2bf(g1[k] * W2[k * 128 + n]);
  } else if (i < 45056) {
    int i3 = i - 36864;
    int n = i3 >> 7, k = i3 & 127;
    wt3[i3] = f2bf(g2[k] * W3[k * 64 + n]);
  }
}

// fold vectors: s2[n]=sum_k g1[k]W2[k,n], c2[n]=sum_k be1[k]W2[k,n]+b2[n]
//               s3[n]=sum_k g2[k]W3[k,n], t3[n]=sum_k be2[k]W3[k,n]
__global__ __launch_bounds__(256) void k_pack_vec(
    const float* __restrict__ W2, const float* __restrict__ W3,
    const float* __restrict__ g1, const float* __restrict__ be1, const float* __restrict__ b2,
    const float* __restrict__ g2, const float* __restrict__ be2,
    float* __restrict__ s2, float* __restrict__ c2,
    float* __restrict__ s3, float* __restrict__ t3) {
  int t = threadIdx.x;
  if (t < 128) {
    float a = 0.f, b = 0.f;
    for (int k = 0; k < 128; ++k) {
      float w = W2[k * 128 + t];
      a += g1[k] * w; b += be1[k] * w;
    }
    s2[t] = a; c2[t] = b + b2[t];
  } else if (t < 192) {
    int n = t - 128;
    float a = 0.f, b = 0.f;
    for (int k = 0; k < 128; ++k) {
      float w = W3[k * 64 + n];
      a += g2[k] * w; b += be2[k] * w;
    }
    s3[n] = a; t3[n] = b;
  }
}

// ---------------- main triplet kernel (transposed / swapped-operand) ----------------
// C' = W^T (A) x X^T (B): C'[hidden n][triplet]. col=lane&15=triplet -> LN stats
// are lane-local over 16 regs + 2 shfl levels. 512 thr = 8 waves (wm:2 n-halves,
// wn:4 triplet-quarters). Per-wave C' tile: 64 n x 32 triplets.

__global__ __launch_bounds__(512, 4) void k_triplet(
    const u16* __restrict__ ebf, const int* __restrict__ tidx,
    const float* __restrict__ geo,
    const u16* __restrict__ wt1, const u16* __restrict__ wt2, const u16* __restrict__ wt3,
    const float* __restrict__ b1,
    const float* __restrict__ s2v, const float* __restrict__ c2v,
    const float* __restrict__ s3v,
    float* __restrict__ psum, float* __restrict__ cnt) {
  extern __shared__ char smem[];
  float* P1S = (float*)(smem + LDS_P1S);
  float* P1Q = (float*)(smem + LDS_P1Q);
  float* P2S = (float*)(smem + LDS_P2S);
  float* P2Q = (float*)(smem + LDS_P2Q);
  int* EIJ = (int*)(smem + LDS_EIJ);
  int* EKJ = (int*)(smem + LDS_EKJ);

  const int tid = threadIdx.x;
  const int wave = tid >> 6, lane = tid & 63;
  const int wm = wave >> 2, wn = wave & 3;
  const int l15 = lane & 15, lg = lane >> 4;
  const int t0 = blockIdx.x * 128;

  if (tid < 128) {
    int2 p = ((const int2*)tidx)[t0 + tid];
    EIJ[tid] = p.x; EKJ[tid] = p.y;
    atomicAdd(&cnt[p.x], 1.0f);
  }
  __syncthreads();

  // stage X = [f_ij | f_kj | geo | 0] as [128][320B]; k<128 swizzled (r&7)<<4,
  // tail 64B swizzled (r&3)<<4
  {
    const int r = tid >> 2, s = tid & 3;
    const int e = (s < 2) ? EIJ[r] : EKJ[r];
    const uint4* src = (const uint4*)(ebf + (size_t)e * 64) + (s & 1) * 4;
    uint4 v0 = src[0], v1 = src[1], v2 = src[2], v3 = src[3];
    const int swz = (r & 7) << 4;
    char* rowp = smem + r * 320;
    *(uint4*)(rowp + ((s * 64 + 0) ^ swz)) = v0;
    *(uint4*)(rowp + ((s * 64 + 16) ^ swz)) = v1;
    *(uint4*)(rowp + ((s * 64 + 32) ^ swz)) = v2;
    *(uint4*)(rowp + ((s * 64 + 48) ^ swz)) = v3;
    const int tswz = (r & 3) << 4;
    if (s == 0) {
      float4 gq = ((const float4*)geo)[t0 + r];
      uint2 gw;
      gw.x = pkbf(gq.x, gq.y); gw.y = pkbf(gq.z, gq.w);
      char* tp = rowp + 256 + (0 ^ tswz);
      *(uint2*)tp = gw;
      *(uint2*)(tp + 8) = (uint2){0, 0};
    } else {
      *(uint4*)(rowp + 256 + ((s * 16) ^ tswz)) = (uint4){0, 0, 0, 0};
    }
  }
  __syncthreads();

  // ---- GEMM1: C1' = W1^T x X^T  (K=160) ----
  f32x4 acc[4][2];
#pragma unroll
  for (int mf = 0; mf < 4; ++mf) { acc[mf][0] = (f32x4)0.f; acc[mf][1] = (f32x4)0.f; }
  const short8* w1p = (const short8*)wt1;
#pragma unroll
  for (int s5 = 0; s5 < 5; ++s5) {
    short8 aw[4], bx[2];
#pragma unroll
    for (int mf = 0; mf < 4; ++mf)
      aw[mf] = w1p[(wm * 64 + mf * 16 + l15) * 20 + s5 * 4 + lg];
#pragma unroll
    for (int f = 0; f < 2; ++f) {
      int trip = wn * 32 + f * 16 + l15;
      int off;
      if (s5 < 4) off = (s5 * 64 + lg * 16) ^ ((trip & 7) << 4);
      else off = 256 + ((lg * 16) ^ ((trip & 3) << 4));
      bx[f] = *(const short8*)(smem + trip * 320 + off);
    }
#pragma unroll
    for (int mf = 0; mf < 4; ++mf) {
      acc[mf][0] = MFMA16(aw[mf], bx[0], acc[mf][0]);
      acc[mf][1] = MFMA16(aw[mf], bx[1], acc[mf][1]);
    }
  }

  // epilogue1: bias+silu in-reg; lane-local stats; write H^T -> [trip][n] bf16
  {
    float4 b1f[4];
#pragma unroll
    for (int mf = 0; mf < 4; ++mf)
      b1f[mf] = *(const float4*)(b1 + wm * 64 + mf * 16 + lg * 4);
    float st[2] = {0.f, 0.f}, sq[2] = {0.f, 0.f};
#pragma unroll
    for (int mf = 0; mf < 4; ++mf)
#pragma unroll
      for (int f = 0; f < 2; ++f)
#pragma unroll
        for (int q = 0; q < 4; ++q) {
          float v = silu(acc[mf][f][q] + b1f[mf][q]);
          acc[mf][f][q] = v;
          st[f] += v; sq[f] += v * v;
        }
#pragma unroll
    for (int f = 0; f < 2; ++f) {
      st[f] += __shfl_xor(st[f], 16); sq[f] += __shfl_xor(sq[f], 16);
      st[f] += __shfl_xor(st[f], 32); sq[f] += __shfl_xor(sq[f], 32);
    }
    if (lg == 0) {
#pragma unroll
      for (int f = 0; f < 2; ++f) {
        int trip = wn * 32 + f * 16 + l15;
        P1S[trip * 2 + wm] = st[f];
        P1Q[trip * 2 + wm] = sq[f];
      }
    }
#pragma unroll
    for (int mf = 0; mf < 4; ++mf)
#pragma unroll
      for (int f = 0; f < 2; ++f) {
        int trip = wn * 32 + f * 16 + l15;
        uint2 w;
        w.x = pkbf(acc[mf][f][0], acc[mf][f][1]);
        w.y = pkbf(acc[mf][f][2], acc[mf][f][3]);
        *(uint2*)(smem + LDS_H + trip * 256 +
                  ((wm * 128 + mf * 32 + lg * 8) ^ ((trip & 7) << 4))) = w;
      }
  }
  __syncthreads();

  // ---- GEMM2: C2' = W2'^T x H^T  (K=128) ----
#pragma unroll
  for (int mf = 0; mf < 4; ++mf) { acc[mf][0] = (f32x4)0.f; acc[mf][1] = (f32x4)0.f; }
  const short8* w2p = (const short8*)wt2;
#pragma unroll
  for (int s4 = 0; s4 < 4; ++s4) {
    short8 aw[4], bx[2];
#pragma unroll
    for (int mf = 0; mf < 4; ++mf)
      aw[mf] = w2p[(wm * 64 + mf * 16 + l15) * 16 + s4 * 4 + lg];
#pragma unroll
    for (int f = 0; f < 2; ++f) {
      int trip = wn * 32 + f * 16 + l15;
      bx[f] = *(const short8*)(smem + LDS_H + trip * 256 +
                               ((s4 * 64 + lg * 16) ^ ((trip & 7) << 4)));
    }
#pragma unroll
    for (int mf = 0; mf < 4; ++mf) {
      acc[mf][0] = MFMA16(aw[mf], bx[0], acc[mf][0]);
      acc[mf][1] = MFMA16(aw[mf], bx[1], acc[mf][1]);
    }
  }

  // epilogue2: folded LN1 + silu; stats; write M^T into [0..32768)
  {
    float4 s2f[4], c2f[4];
#pragma unroll
    for (int mf = 0; mf < 4; ++mf) {
      s2f[mf] = *(const float4*)(s2v + wm * 64 + mf * 16 + lg * 4);
      c2f[mf] = *(const float4*)(c2v + wm * 64 + mf * 16 + lg * 4);
    }
    float mu[2], inv[2];
#pragma unroll
    for (int f = 0; f < 2; ++f) {
      int trip = wn * 32 + f * 16 + l15;
      float sm = P1S[trip * 2] + P1S[trip * 2 + 1];
      float qq = P1Q[trip * 2] + P1Q[trip * 2 + 1];
      mu[f] = sm * 0.0078125f;
      inv[f] = rsqrtf(fmaxf(qq * 0.0078125f - mu[f] * mu[f], 0.f) + 1e-5f);
    }
    float st[2] = {0.f, 0.f}, sq[2] = {0.f, 0.f};
#pragma unroll
    for (int mf = 0; mf < 4; ++mf)
#pragma unroll
      for (int f = 0; f < 2; ++f)
#pragma unroll
        for (int q = 0; q < 4; ++q) {
          float y = inv[f] * (acc[mf][f][q] - mu[f] * s2f[mf][q]) + c2f[mf][q];
          float v = silu(y);
          acc[mf][f][q] = v;
          st[f] += v; sq[f] += v * v;
        }
#pragma unroll
    for (int f = 0; f < 2; ++f) {
      st[f] += __shfl_xor(st[f], 16); sq[f] += __shfl_xor(sq[f], 16);
      st[f] += __shfl_xor(st[f], 32); sq[f] += __shfl_xor(sq[f], 32);
    }
    if (lg == 0) {
#pragma unroll
      for (int f = 0; f < 2; ++f) {
        int trip = wn * 32 + f * 16 + l15;
        P2S[trip * 2 + wm] = st[f];
        P2Q[trip * 2 + wm] = sq[f];
      }
    }
#pragma unroll
    for (int mf = 0; mf < 4; ++mf)
#pragma unroll
      for (int f = 0; f < 2; ++f) {
        int trip = wn * 32 + f * 16 + l15;
        uint2 w;
        w.x = pkbf(acc[mf][f][0], acc[mf][f][1]);
        w.y = pkbf(acc[mf][f][2], acc[mf][f][3]);
        *(uint2*)(smem + trip * 256 +
                  ((wm * 128 + mf * 32 + lg * 8) ^ ((trip & 7) << 4))) = w;
      }
  }
  __syncthreads();

  // ---- GEMM3: C3' = W3'^T x M^T  (K=128, n3=64) + folded LN2 + atomic scatter ----
  f32x4 acc3[2][2];
#pragma unroll
  for (int mf = 0; mf < 2; ++mf) { acc3[mf][0] = (f32x4)0.f; acc3[mf][1] = (f32x4)0.f; }
  const short8* w3p = (const short8*)wt3;
#pragma unroll
  for (int s4 = 0; s4 < 4; ++s4) {
    short8 aw[2], bx[2];
#pragma unroll
    for (int mf = 0; mf < 2; ++mf)
      aw[mf] = w3p[(wm * 32 + mf * 16 + l15) * 16 + s4 * 4 + lg];
#pragma unroll
    for (int f = 0; f < 2; ++f) {
      int trip = wn * 32 + f * 16 + l15;
      bx[f] = *(const short8*)(smem + trip * 256 +
                               ((s4 * 64 + lg * 16) ^ ((trip & 7) << 4)));
    }
#pragma unroll
    for (int mf = 0; mf < 2; ++mf) {
      acc3[mf][0] = MFMA16(aw[mf], bx[0], acc3[mf][0]);
      acc3[mf][1] = MFMA16(aw[mf], bx[1], acc3[mf][1]);
    }
  }
  {
    float4 s3f[2];
#pragma unroll
    for (int mf = 0; mf < 2; ++mf)
      s3f[mf] = *(const float4*)(s3v + wm * 32 + mf * 16 + lg * 4);
    float mu3[2], inv3[2];
    int ei[2];
#pragma unroll
    for (int f = 0; f < 2; ++f) {
      int trip = wn * 32 + f * 16 + l15;
      float sm = P2S[trip * 2] + P2S[trip * 2 + 1];
      float qq = P2Q[trip * 2] + P2Q[trip * 2 + 1];
      mu3[f] = sm * 0.0078125f;
      inv3[f] = rsqrtf(fmaxf(qq * 0.0078125f - mu3[f] * mu3[f], 0.f) + 1e-5f);
      ei[f] = EIJ[trip];
    }
#pragma unroll
    for (int mf = 0; mf < 2; ++mf)
#pragma unroll
      for (int f = 0; f < 2; ++f)
#pragma unroll
        for (int q = 0; q < 4; ++q) {
          float y = inv3[f] * (acc3[mf][f][q] - mu3[f] * s3f[mf][q]);
          int n3 = wm * 32 + mf * 16 + lg * 4 + q;
          atomicAdd(psum + (size_t)ei[f] * 64 + n3, y);
        }
  }
}

// ---------------- finalize ----------------
// out = LN(ef + psum/max(cnt,1) + b3 + (cnt>0 ? t3 : 0), gn, bn)

__global__ __launch_bounds__(256) void k_final(
    const float* __restrict__ psum, const float* __restrict__ cnt,
    const float* __restrict__ ef, const float* __restrict__ b3,
    const float* __restrict__ t3, const float* __restrict__ gn,
    const float* __restrict__ bn, float* __restrict__ out) {
  int g = blockIdx.x * 256 + threadIdx.x;  // 4e6 threads, 4 lanes/edge
  int e = g >> 2, s = g & 3;
  float cv = cnt[e];
  float ic = 1.0f / fmaxf(cv, 1.0f);
  float tw = (cv > 0.f) ? 1.0f : 0.0f;
  float x[16];
  const float4* ps = (const float4*)(psum + (size_t)e * 64 + s * 16);
  const float4* fe = (const float4*)(ef + (size_t)e * 64 + s * 16);
  const float4* p3 = (const float4*)(b3 + s * 16);
  const float4* pt = (const float4*)(t3 + s * 16);
#pragma unroll
  for (int i = 0; i < 4; ++i) {
    float4 a = ps[i], b = fe[i], c = p3[i], d = pt[i];
    x[4 * i + 0] = b.x + a.x * ic + c.x + tw * d.x;
    x[4 * i + 1] = b.y + a.y * ic + c.y + tw * d.y;
    x[4 * i + 2] = b.z + a.z * ic + c.z + tw * d.z;
    x[4 * i + 3] = b.w + a.w * ic + c.w + tw * d.w;
  }
  float sum = 0.f, ss = 0.f;
#pragma unroll
  for (int i = 0; i < 16; ++i) { sum += x[i]; ss += x[i] * x[i]; }
  sum += __shfl_xor(sum, 1); ss += __shfl_xor(ss, 1);
  sum += __shfl_xor(sum, 2); ss += __shfl_xor(ss, 2);
  float mu = sum * (1.0f / 64.0f);
  float inv = rsqrtf(ss * (1.0f / 64.0f) - mu * mu + 1e-5f);
  float4* po = (float4*)(out + (size_t)e * 64 + s * 16);
#pragma unroll
  for (int i = 0; i < 4; ++i) {
    float4 gv = ((const float4*)(gn + s * 16))[i];
    float4 bv = ((const float4*)(bn + s * 16))[i];
    float4 o;
    o.x = (x[4 * i + 0] - mu) * inv * gv.x + bv.x;
    o.y = (x[4 * i + 1] - mu) * inv * gv.y + bv.y;
    o.z = (x[4 * i + 2] - mu) * inv * gv.z + bv.z;
    o.w = (x[4 * i + 3] - mu) * inv * gv.w + bv.w;
    po[i] = o;
  }
}

extern "C" void kernel_launch(void* const* d_in, const int* in_sizes, int n_in,
                              void* d_out, int out_size, void* d_ws, size_t ws_size,
                              hipStream_t stream) {
  const float* edge_feat = (const float*)d_in[0];
  const int* tidx = (const int*)d_in[1];
  const float* geo = (const float*)d_in[2];
  const float* W1 = (const float*)d_in[3];
  const float* b1 = (const float*)d_in[4];
  const float* g1 = (const float*)d_in[5];
  const float* be1 = (const float*)d_in[6];
  const float* W2 = (const float*)d_in[7];
  const float* b2 = (const float*)d_in[8];
  const float* g2 = (const float*)d_in[9];
  const float* be2 = (const float*)d_in[10];
  const float* W3 = (const float*)d_in[11];
  const float* b3 = (const float*)d_in[12];
  const float* gn = (const float*)d_in[13];
  const float* bn = (const float*)d_in[14];

  char* ws = (char*)d_ws;
  float* psum = (float*)(ws + OFF_PSUM);
  float* cnt = (float*)(ws + OFF_CNT);
  u16* ebf = (u16*)(ws + OFF_EBF);
  u16* wt1 = (u16*)(ws + OFF_WT1);
  u16* wt2 = (u16*)(ws + OFF_WT2);
  u16* wt3 = (u16*)(ws + OFF_WT3);
  float* s2 = (float*)(ws + OFF_S2);
  float* c2 = (float*)(ws + OFF_C2);
  float* s3 = (float*)(ws + OFF_S3);
  float* t3 = (float*)(ws + OFF_T3);
  float* out = (float*)d_out;

  hipMemsetAsync(ws, 0, 260000000ULL, stream);  // psum + cnt
  k_conv_edge<<<62500, 256, 0, stream>>>(edge_feat, ebf);
  k_pack_w<<<176, 256, 0, stream>>>(W1, W2, W3, g1, g2, wt1, wt2, wt3);
  k_pack_vec<<<1, 256, 0, stream>>>(W2, W3, g1, be1, b2, g2, be2, s2, c2, s3, t3);

  hipFuncSetAttribute((const void*)k_triplet,
                      hipFuncAttributeMaxDynamicSharedMemorySize, LDS_TOTAL);
  k_triplet<<<15625, 512, LDS_TOTAL, stream>>>(ebf, tidx, geo, wt1, wt2, wt3,
                                               b1, s2, c2, s3, psum, cnt);
  k_final<<<15625, 256, 0, stream>>>(psum, cnt, edge_feat, b3, t3, gn, bn, out);
}

// Round 4
// 1148.364 us; speedup vs baseline: 1.8396x; 1.8396x over previous
//
#include <hip/hip_runtime.h>
#include <hip/hip_bf16.h>
#include <stdint.h>

typedef __attribute__((ext_vector_type(8))) short short8;
typedef __attribute__((ext_vector_type(4))) float f32x4;
typedef unsigned short u16;

// ---------------- workspace layout (bytes) ----------------
#define OFF_PSUM 0ULL                      // 1e6*64*4 = 256,000,000
#define OFF_CNT  256000000ULL              // 1e6*4
#define OFF_EBF  260000000ULL              // 1e6*64*2 = 128,000,000
#define OFF_WT1  388000000ULL              // W1^T row-major [n][k]: 128*160*2 = 40960
#define OFF_WT2  (OFF_WT1 + 40960ULL)      // W2'^T row-major [n][k]: 128*128*2 = 32768
#define OFF_WP3  (OFF_WT2 + 32768ULL)      // W3' frag-packed [kb][n][8]: 16384
#define OFF_S2   (OFF_WP3 + 16384ULL)      // 128*4
#define OFF_C2   (OFF_S2 + 512ULL)         // 128*4
#define OFF_S3   (OFF_C2 + 512ULL)         // 64*4
#define OFF_T3   (OFF_S3 + 256ULL)         // 64*4

// ---------------- LDS layout (bytes) ----------------
// X: [128 trip][320B] swizzled; M later aliases [0..32768) as [trip][256B] swizzled
// H: [128 trip][256B] swizzled at LDS_H
#define LDS_H   40960
#define LDS_P1S 73728   // float[128][2]
#define LDS_P1Q 74752
#define LDS_P2S 75776
#define LDS_P2Q 76800
#define LDS_EIJ 77824   // int[128]
#define LDS_EKJ 78336
#define LDS_TOTAL 78848

__device__ __forceinline__ u16 f2bf(float f) {
  union { float f; uint32_t u; } c; c.f = f;
  uint32_t u = c.u;
  return (u16)((u + 0x7FFFu + ((u >> 16) & 1u)) >> 16);  // RNE
}
__device__ __forceinline__ uint32_t pkbf(float lo, float hi) {
  float2 t; t.x = lo; t.y = hi;
  __hip_bfloat162 h = __float22bfloat162_rn(t);
  uint32_t u; __builtin_memcpy(&u, &h, 4);
  return u;
}
__device__ __forceinline__ float silu(float y) {
  return y * __builtin_amdgcn_rcpf(1.0f + __expf(-y));
}

#define MFMA16(a, b, c) __builtin_amdgcn_mfma_f32_16x16x32_bf16((a), (b), (c), 0, 0, 0)

// ---------------- prep kernels ----------------

__global__ __launch_bounds__(256) void k_conv_edge(const float* __restrict__ ef,
                                                   u16* __restrict__ ebf) {
  int i = blockIdx.x * 256 + threadIdx.x;  // < 16,000,000
  float4 v = ((const float4*)ef)[i];
  ushort4 o;
  o.x = f2bf(v.x); o.y = f2bf(v.y); o.z = f2bf(v.z); o.w = f2bf(v.w);
  ((ushort4*)ebf)[i] = o;
}

// wt1[n*160+k] = W1[k,n] (k<132 else 0)   [transposed row-major]
// wt2[n*128+k] = g1[k]*W2[k,n]            [transposed row-major]
// wp3[(k>>3)*64 + n][k&7] = g2[k]*W3[k,n] [B-fragment packed]
__global__ __launch_bounds__(256) void k_pack_w(const float* __restrict__ W1,
                                                const float* __restrict__ W2,
                                                const float* __restrict__ W3,
                                                const float* __restrict__ g1,
                                                const float* __restrict__ g2,
                                                u16* __restrict__ wt1,
                                                u16* __restrict__ wt2,
                                                u16* __restrict__ wp3) {
  int i = blockIdx.x * 256 + threadIdx.x;  // < 45056
  if (i < 20480) {
    int n = i / 160, k = i - n * 160;
    wt1[i] = (k < 132) ? f2bf(W1[k * 128 + n]) : (u16)0;
  } else if (i < 36864) {
    int i2 = i - 20480;
    int n = i2 >> 7, k = i2 & 127;
    wt2[i2] = f2bf(g1[k] * W2[k * 128 + n]);
  } else if (i < 45056) {
    int i3 = i - 36864;
    int j = i3 & 7, n = (i3 >> 3) & 63, kb = i3 >> 9;
    int k = kb * 8 + j;
    wp3[i3] = f2bf(g2[k] * W3[k * 64 + n]);
  }
}

// fold vectors: s2[n]=sum_k g1[k]W2[k,n], c2[n]=sum_k be1[k]W2[k,n]+b2[n]
//               s3[n]=sum_k g2[k]W3[k,n], t3[n]=sum_k be2[k]W3[k,n]
__global__ __launch_bounds__(256) void k_pack_vec(
    const float* __restrict__ W2, const float* __restrict__ W3,
    const float* __restrict__ g1, const float* __restrict__ be1, const float* __restrict__ b2,
    const float* __restrict__ g2, const float* __restrict__ be2,
    float* __restrict__ s2, float* __restrict__ c2,
    float* __restrict__ s3, float* __restrict__ t3) {
  int t = threadIdx.x;
  if (t < 128) {
    float a = 0.f, b = 0.f;
    for (int k = 0; k < 128; ++k) {
      float w = W2[k * 128 + t];
      a += g1[k] * w; b += be1[k] * w;
    }
    s2[t] = a; c2[t] = b + b2[t];
  } else if (t < 192) {
    int n = t - 128;
    float a = 0.f, b = 0.f;
    for (int k = 0; k < 128; ++k) {
      float w = W3[k * 64 + n];
      a += g2[k] * w; b += be2[k] * w;
    }
    s3[n] = a; t3[n] = b;
  }
}

// ---------------- main triplet kernel ----------------
// GEMM1/2 transposed (C' = W^T x X^T, lane-local LN stats); M stored [trip][n]
// row-major = normal-orientation A; GEMM3 un-transposed (C3: row=trip, col=n)
// -> coalesced atomic scatter (4 edges x 16 consecutive floats per instr).

__global__ __launch_bounds__(512, 4) void k_triplet(
    const u16* __restrict__ ebf, const int* __restrict__ tidx,
    const float* __restrict__ geo,
    const u16* __restrict__ wt1, const u16* __restrict__ wt2, const u16* __restrict__ wp3,
    const float* __restrict__ b1,
    const float* __restrict__ s2v, const float* __restrict__ c2v,
    const float* __restrict__ s3v,
    float* __restrict__ psum, float* __restrict__ cnt) {
  extern __shared__ char smem[];
  float* P1S = (float*)(smem + LDS_P1S);
  float* P1Q = (float*)(smem + LDS_P1Q);
  float* P2S = (float*)(smem + LDS_P2S);
  float* P2Q = (float*)(smem + LDS_P2Q);
  int* EIJ = (int*)(smem + LDS_EIJ);
  int* EKJ = (int*)(smem + LDS_EKJ);

  const int tid = threadIdx.x;
  const int wave = tid >> 6, lane = tid & 63;
  const int wm = wave >> 2, wn = wave & 3;
  const int l15 = lane & 15, lg = lane >> 4;
  const int t0 = blockIdx.x * 128;

  if (tid < 128) {
    int2 p = ((const int2*)tidx)[t0 + tid];
    EIJ[tid] = p.x; EKJ[tid] = p.y;
    atomicAdd(&cnt[p.x], 1.0f);
  }
  __syncthreads();

  // stage X = [f_ij | f_kj | geo | 0] as [128][320B]; k<128 swizzled (r&7)<<4,
  // tail 64B swizzled (r&3)<<4
  {
    const int r = tid >> 2, s = tid & 3;
    const int e = (s < 2) ? EIJ[r] : EKJ[r];
    const uint4* src = (const uint4*)(ebf + (size_t)e * 64) + (s & 1) * 4;
    uint4 v0 = src[0], v1 = src[1], v2 = src[2], v3 = src[3];
    const int swz = (r & 7) << 4;
    char* rowp = smem + r * 320;
    *(uint4*)(rowp + ((s * 64 + 0) ^ swz)) = v0;
    *(uint4*)(rowp + ((s * 64 + 16) ^ swz)) = v1;
    *(uint4*)(rowp + ((s * 64 + 32) ^ swz)) = v2;
    *(uint4*)(rowp + ((s * 64 + 48) ^ swz)) = v3;
    const int tswz = (r & 3) << 4;
    if (s == 0) {
      float4 gq = ((const float4*)geo)[t0 + r];
      uint2 gw;
      gw.x = pkbf(gq.x, gq.y); gw.y = pkbf(gq.z, gq.w);
      char* tp = rowp + 256 + (0 ^ tswz);
      *(uint2*)tp = gw;
      *(uint2*)(tp + 8) = (uint2){0, 0};
    } else {
      *(uint4*)(rowp + 256 + ((s * 16) ^ tswz)) = (uint4){0, 0, 0, 0};
    }
  }
  __syncthreads();

  // ---- GEMM1: C1' = W1^T x X^T  (K=160) ----
  f32x4 acc[4][2];
#pragma unroll
  for (int mf = 0; mf < 4; ++mf) { acc[mf][0] = (f32x4)0.f; acc[mf][1] = (f32x4)0.f; }
  const short8* w1p = (const short8*)wt1;
#pragma unroll
  for (int s5 = 0; s5 < 5; ++s5) {
    short8 aw[4], bx[2];
#pragma unroll
    for (int mf = 0; mf < 4; ++mf)
      aw[mf] = w1p[(wm * 64 + mf * 16 + l15) * 20 + s5 * 4 + lg];
#pragma unroll
    for (int f = 0; f < 2; ++f) {
      int trip = wn * 32 + f * 16 + l15;
      int off;
      if (s5 < 4) off = (s5 * 64 + lg * 16) ^ ((trip & 7) << 4);
      else off = 256 + ((lg * 16) ^ ((trip & 3) << 4));
      bx[f] = *(const short8*)(smem + trip * 320 + off);
    }
#pragma unroll
    for (int mf = 0; mf < 4; ++mf) {
      acc[mf][0] = MFMA16(aw[mf], bx[0], acc[mf][0]);
      acc[mf][1] = MFMA16(aw[mf], bx[1], acc[mf][1]);
    }
  }

  // epilogue1: bias+silu in-reg; lane-local stats; write H^T -> [trip][n] bf16
  {
    float4 b1f[4];
#pragma unroll
    for (int mf = 0; mf < 4; ++mf)
      b1f[mf] = *(const float4*)(b1 + wm * 64 + mf * 16 + lg * 4);
    float st[2] = {0.f, 0.f}, sq[2] = {0.f, 0.f};
#pragma unroll
    for (int mf = 0; mf < 4; ++mf)
#pragma unroll
      for (int f = 0; f < 2; ++f)
#pragma unroll
        for (int q = 0; q < 4; ++q) {
          float v = silu(acc[mf][f][q] + b1f[mf][q]);
          acc[mf][f][q] = v;
          st[f] += v; sq[f] += v * v;
        }
#pragma unroll
    for (int f = 0; f < 2; ++f) {
      st[f] += __shfl_xor(st[f], 16); sq[f] += __shfl_xor(sq[f], 16);
      st[f] += __shfl_xor(st[f], 32); sq[f] += __shfl_xor(sq[f], 32);
    }
    if (lg == 0) {
#pragma unroll
      for (int f = 0; f < 2; ++f) {
        int trip = wn * 32 + f * 16 + l15;
        P1S[trip * 2 + wm] = st[f];
        P1Q[trip * 2 + wm] = sq[f];
      }
    }
#pragma unroll
    for (int mf = 0; mf < 4; ++mf)
#pragma unroll
      for (int f = 0; f < 2; ++f) {
        int trip = wn * 32 + f * 16 + l15;
        uint2 w;
        w.x = pkbf(acc[mf][f][0], acc[mf][f][1]);
        w.y = pkbf(acc[mf][f][2], acc[mf][f][3]);
        *(uint2*)(smem + LDS_H + trip * 256 +
                  ((wm * 128 + mf * 32 + lg * 8) ^ ((trip & 7) << 4))) = w;
      }
  }
  __syncthreads();

  // ---- GEMM2: C2' = W2'^T x H^T  (K=128) ----
#pragma unroll
  for (int mf = 0; mf < 4; ++mf) { acc[mf][0] = (f32x4)0.f; acc[mf][1] = (f32x4)0.f; }
  const short8* w2p = (const short8*)wt2;
#pragma unroll
  for (int s4 = 0; s4 < 4; ++s4) {
    short8 aw[4], bx[2];
#pragma unroll
    for (int mf = 0; mf < 4; ++mf)
      aw[mf] = w2p[(wm * 64 + mf * 16 + l15) * 16 + s4 * 4 + lg];
#pragma unroll
    for (int f = 0; f < 2; ++f) {
      int trip = wn * 32 + f * 16 + l15;
      bx[f] = *(const short8*)(smem + LDS_H + trip * 256 +
                               ((s4 * 64 + lg * 16) ^ ((trip & 7) << 4)));
    }
#pragma unroll
    for (int mf = 0; mf < 4; ++mf) {
      acc[mf][0] = MFMA16(aw[mf], bx[0], acc[mf][0]);
      acc[mf][1] = MFMA16(aw[mf], bx[1], acc[mf][1]);
    }
  }

  // epilogue2: folded LN1 + silu; lane-local stats; write M [trip][n] into [0..32768)
  {
    float4 s2f[4], c2f[4];
#pragma unroll
    for (int mf = 0; mf < 4; ++mf) {
      s2f[mf] = *(const float4*)(s2v + wm * 64 + mf * 16 + lg * 4);
      c2f[mf] = *(const float4*)(c2v + wm * 64 + mf * 16 + lg * 4);
    }
    float mu[2], inv[2];
#pragma unroll
    for (int f = 0; f < 2; ++f) {
      int trip = wn * 32 + f * 16 + l15;
      float sm = P1S[trip * 2] + P1S[trip * 2 + 1];
      float qq = P1Q[trip * 2] + P1Q[trip * 2 + 1];
      mu[f] = sm * 0.0078125f;
      inv[f] = rsqrtf(fmaxf(qq * 0.0078125f - mu[f] * mu[f], 0.f) + 1e-5f);
    }
    float st[2] = {0.f, 0.f}, sq[2] = {0.f, 0.f};
#pragma unroll
    for (int mf = 0; mf < 4; ++mf)
#pragma unroll
      for (int f = 0; f < 2; ++f)
#pragma unroll
        for (int q = 0; q < 4; ++q) {
          float y = inv[f] * (acc[mf][f][q] - mu[f] * s2f[mf][q]) + c2f[mf][q];
          float v = silu(y);
          acc[mf][f][q] = v;
          st[f] += v; sq[f] += v * v;
        }
#pragma unroll
    for (int f = 0; f < 2; ++f) {
      st[f] += __shfl_xor(st[f], 16); sq[f] += __shfl_xor(sq[f], 16);
      st[f] += __shfl_xor(st[f], 32); sq[f] += __shfl_xor(sq[f], 32);
    }
    if (lg == 0) {
#pragma unroll
      for (int f = 0; f < 2; ++f) {
        int trip = wn * 32 + f * 16 + l15;
        P2S[trip * 2 + wm] = st[f];
        P2Q[trip * 2 + wm] = sq[f];
      }
    }
#pragma unroll
    for (int mf = 0; mf < 4; ++mf)
#pragma unroll
      for (int f = 0; f < 2; ++f) {
        int trip = wn * 32 + f * 16 + l15;
        uint2 w;
        w.x = pkbf(acc[mf][f][0], acc[mf][f][1]);
        w.y = pkbf(acc[mf][f][2], acc[mf][f][3]);
        *(uint2*)(smem + trip * 256 +
                  ((wm * 128 + mf * 32 + lg * 8) ^ ((trip & 7) << 4))) = w;
      }
  }

  // prefetch GEMM3 B frags (normal orientation, fragment-packed) + s3
  const short8* wb3 = (const short8*)wp3;
  const int n3 = wn * 16 + l15;
  short8 w3f[4];
#pragma unroll
  for (int s4 = 0; s4 < 4; ++s4) w3f[s4] = wb3[(s4 * 4 + lg) * 64 + n3];
  float s3c = s3v[n3];

  __syncthreads();  // M visible

  // ---- GEMM3 (un-transposed): C3 = M x W3'  (K=128, N=64) ----
  f32x4 acc3[4];
#pragma unroll
  for (int mf = 0; mf < 4; ++mf) acc3[mf] = (f32x4)0.f;
#pragma unroll
  for (int s4 = 0; s4 < 4; ++s4) {
    short8 a[4];
#pragma unroll
    for (int mf = 0; mf < 4; ++mf) {
      int row = wm * 64 + mf * 16 + l15;
      a[mf] = *(const short8*)(smem + row * 256 +
                               ((s4 * 64 + lg * 16) ^ ((row & 7) << 4)));
    }
#pragma unroll
    for (int mf = 0; mf < 4; ++mf) acc3[mf] = MFMA16(a[mf], w3f[s4], acc3[mf]);
  }

  // folded LN2 + coalesced atomic scatter (row=trip, col=n3)
#pragma unroll
  for (int mf = 0; mf < 4; ++mf)
#pragma unroll
    for (int q = 0; q < 4; ++q) {
      int row = wm * 64 + mf * 16 + lg * 4 + q;
      float sm = P2S[row * 2] + P2S[row * 2 + 1];
      float qq = P2Q[row * 2] + P2Q[row * 2 + 1];
      float mu = sm * 0.0078125f;
      float inv = rsqrtf(fmaxf(qq * 0.0078125f - mu * mu, 0.f) + 1e-5f);
      float y = inv * (acc3[mf][q] - mu * s3c);
      int e = EIJ[row];
      atomicAdd(psum + (size_t)e * 64 + n3, y);
    }
}

// ---------------- finalize ----------------
// out = LN(ef + psum/max(cnt,1) + b3 + (cnt>0 ? t3 : 0), gn, bn)

__global__ __launch_bounds__(256) void k_final(
    const float* __restrict__ psum, const float* __restrict__ cnt,
    const float* __restrict__ ef, const float* __restrict__ b3,
    const float* __restrict__ t3, const float* __restrict__ gn,
    const float* __restrict__ bn, float* __restrict__ out) {
  int g = blockIdx.x * 256 + threadIdx.x;  // 4e6 threads, 4 lanes/edge
  int e = g >> 2, s = g & 3;
  float cv = cnt[e];
  float ic = 1.0f / fmaxf(cv, 1.0f);
  float tw = (cv > 0.f) ? 1.0f : 0.0f;
  float x[16];
  const float4* ps = (const float4*)(psum + (size_t)e * 64 + s * 16);
  const float4* fe = (const float4*)(ef + (size_t)e * 64 + s * 16);
  const float4* p3 = (const float4*)(b3 + s * 16);
  const float4* pt = (const float4*)(t3 + s * 16);
#pragma unroll
  for (int i = 0; i < 4; ++i) {
    float4 a = ps[i], b = fe[i], c = p3[i], d = pt[i];
    x[4 * i + 0] = b.x + a.x * ic + c.x + tw * d.x;
    x[4 * i + 1] = b.y + a.y * ic + c.y + tw * d.y;
    x[4 * i + 2] = b.z + a.z * ic + c.z + tw * d.z;
    x[4 * i + 3] = b.w + a.w * ic + c.w + tw * d.w;
  }
  float sum = 0.f, ss = 0.f;
#pragma unroll
  for (int i = 0; i < 16; ++i) { sum += x[i]; ss += x[i] * x[i]; }
  sum += __shfl_xor(sum, 1); ss += __shfl_xor(ss, 1);
  sum += __shfl_xor(sum, 2); ss += __shfl_xor(ss, 2);
  float mu = sum * (1.0f / 64.0f);
  float inv = rsqrtf(ss * (1.0f / 64.0f) - mu * mu + 1e-5f);
  float4* po = (float4*)(out + (size_t)e * 64 + s * 16);
#pragma unroll
  for (int i = 0; i < 4; ++i) {
    float4 gv = ((const float4*)(gn + s * 16))[i];
    float4 bv = ((const float4*)(bn + s * 16))[i];
    float4 o;
    o.x = (x[4 * i + 0] - mu) * inv * gv.x + bv.x;
    o.y = (x[4 * i + 1] - mu) * inv * gv.y + bv.y;
    o.z = (x[4 * i + 2] - mu) * inv * gv.z + bv.z;
    o.w = (x[4 * i + 3] - mu) * inv * gv.w + bv.w;
    po[i] = o;
  }
}

extern "C" void kernel_launch(void* const* d_in, const int* in_sizes, int n_in,
                              void* d_out, int out_size, void* d_ws, size_t ws_size,
                              hipStream_t stream) {
  const float* edge_feat = (const float*)d_in[0];
  const int* tidx = (const int*)d_in[1];
  const float* geo = (const float*)d_in[2];
  const float* W1 = (const float*)d_in[3];
  const float* b1 = (const float*)d_in[4];
  const float* g1 = (const float*)d_in[5];
  const float* be1 = (const float*)d_in[6];
  const float* W2 = (const float*)d_in[7];
  const float* b2 = (const float*)d_in[8];
  const float* g2 = (const float*)d_in[9];
  const float* be2 = (const float*)d_in[10];
  const float* W3 = (const float*)d_in[11];
  const float* b3 = (const float*)d_in[12];
  const float* gn = (const float*)d_in[13];
  const float* bn = (const float*)d_in[14];

  char* ws = (char*)d_ws;
  float* psum = (float*)(ws + OFF_PSUM);
  float* cnt = (float*)(ws + OFF_CNT);
  u16* ebf = (u16*)(ws + OFF_EBF);
  u16* wt1 = (u16*)(ws + OFF_WT1);
  u16* wt2 = (u16*)(ws + OFF_WT2);
  u16* wp3 = (u16*)(ws + OFF_WP3);
  float* s2 = (float*)(ws + OFF_S2);
  float* c2 = (float*)(ws + OFF_C2);
  float* s3 = (float*)(ws + OFF_S3);
  float* t3 = (float*)(ws + OFF_T3);
  float* out = (float*)d_out;

  hipMemsetAsync(ws, 0, 260000000ULL, stream);  // psum + cnt
  k_conv_edge<<<62500, 256, 0, stream>>>(edge_feat, ebf);
  k_pack_w<<<176, 256, 0, stream>>>(W1, W2, W3, g1, g2, wt1, wt2, wp3);
  k_pack_vec<<<1, 256, 0, stream>>>(W2, W3, g1, be1, b2, g2, be2, s2, c2, s3, t3);

  hipFuncSetAttribute((const void*)k_triplet,
                      hipFuncAttributeMaxDynamicSharedMemorySize, LDS_TOTAL);
  k_triplet<<<15625, 512, LDS_TOTAL, stream>>>(ebf, tidx, geo, wt1, wt2, wp3,
                                               b1, s2, c2, s3, psum, cnt);
  k_final<<<15625, 256, 0, stream>>>(psum, cnt, edge_feat, b3, t3, gn, bn, out);
}

// Round 5
// 1062.975 us; speedup vs baseline: 1.9874x; 1.0803x over previous
//
#include <hip/hip_runtime.h>
#include <hip/hip_bf16.h>
#include <stdint.h>

typedef __attribute__((ext_vector_type(8))) short short8;
typedef __attribute__((ext_vector_type(4))) float f32x4;
typedef unsigned short u16;

// ---------------- workspace layout (bytes) ----------------
#define OFF_PSUM 0ULL                      // 1e6*64*4 = 256,000,000
#define OFF_CNT  256000000ULL              // 1e6*4
#define OFF_EBF  260000000ULL              // 1e6*64*2 = 128,000,000
#define OFF_WT1  388000000ULL              // W1^T row-major [n][k]: 128*160*2 = 40960
#define OFF_WT2  (OFF_WT1 + 40960ULL)      // W2'^T row-major [n][k]: 128*128*2 = 32768
#define OFF_WP3  (OFF_WT2 + 32768ULL)      // W3' frag-packed [kb][n][8]: 16384
#define OFF_S2   (OFF_WP3 + 16384ULL)      // 128*4
#define OFF_C2   (OFF_S2 + 512ULL)         // 128*4
#define OFF_S3   (OFF_C2 + 512ULL)         // 64*4
#define OFF_T3   (OFF_S3 + 256ULL)         // 64*4

// ---------------- LDS layout (bytes), 64-trip block ----------------
// H region [64 trip][256B] swizzled; M aliases it after GEMM2.
#define LDS_HM   0        // 16384
#define LDS_TAIL 16384    // [64 trip][64B] geo tail, swizzled (r&3)<<4 -> 4096
#define LDS_P1S  20480    // float[64][2]
#define LDS_P1Q  20992
#define LDS_P2S  21504
#define LDS_P2Q  22016
#define LDS_EIJ  22528    // int[64]
#define LDS_TOTAL 22784

__device__ __forceinline__ u16 f2bf(float f) {
  union { float f; uint32_t u; } c; c.f = f;
  uint32_t u = c.u;
  return (u16)((u + 0x7FFFu + ((u >> 16) & 1u)) >> 16);  // RNE
}
__device__ __forceinline__ uint32_t pkbf(float lo, float hi) {
  float2 t; t.x = lo; t.y = hi;
  __hip_bfloat162 h = __float22bfloat162_rn(t);
  uint32_t u; __builtin_memcpy(&u, &h, 4);
  return u;
}
__device__ __forceinline__ float silu(float y) {
  return y * __builtin_amdgcn_rcpf(1.0f + __expf(-y));
}

#define MFMA16(a, b, c) __builtin_amdgcn_mfma_f32_16x16x32_bf16((a), (b), (c), 0, 0, 0)

// ---------------- prep kernels ----------------

__global__ __launch_bounds__(256) void k_conv_edge(const float* __restrict__ ef,
                                                   u16* __restrict__ ebf) {
  int i = blockIdx.x * 256 + threadIdx.x;  // < 16,000,000
  float4 v = ((const float4*)ef)[i];
  ushort4 o;
  o.x = f2bf(v.x); o.y = f2bf(v.y); o.z = f2bf(v.z); o.w = f2bf(v.w);
  ((ushort4*)ebf)[i] = o;
}

// wt1[n*160+k] = W1[k,n] (k<132 else 0)   [transposed row-major]
// wt2[n*128+k] = g1[k]*W2[k,n]            [transposed row-major]
// wp3[(k>>3)*64 + n][k&7] = g2[k]*W3[k,n] [B-fragment packed]
__global__ __launch_bounds__(256) void k_pack_w(const float* __restrict__ W1,
                                                const float* __restrict__ W2,
                                                const float* __restrict__ W3,
                                                const float* __restrict__ g1,
                                                const float* __restrict__ g2,
                                                u16* __restrict__ wt1,
                                                u16* __restrict__ wt2,
                                                u16* __restrict__ wp3) {
  int i = blockIdx.x * 256 + threadIdx.x;  // < 45056
  if (i < 20480) {
    int n = i / 160, k = i - n * 160;
    wt1[i] = (k < 132) ? f2bf(W1[k * 128 + n]) : (u16)0;
  } else if (i < 36864) {
    int i2 = i - 20480;
    int n = i2 >> 7, k = i2 & 127;
    wt2[i2] = f2bf(g1[k] * W2[k * 128 + n]);
  } else if (i < 45056) {
    int i3 = i - 36864;
    int j = i3 & 7, n = (i3 >> 3) & 63, kb = i3 >> 9;
    int k = kb * 8 + j;
    wp3[i3] = f2bf(g2[k] * W3[k * 64 + n]);
  }
}

// fold vectors: s2[n]=sum_k g1[k]W2[k,n], c2[n]=sum_k be1[k]W2[k,n]+b2[n]
//               s3[n]=sum_k g2[k]W3[k,n], t3[n]=sum_k be2[k]W3[k,n]
__global__ __launch_bounds__(256) void k_pack_vec(
    const float* __restrict__ W2, const float* __restrict__ W3,
    const float* __restrict__ g1, const float* __restrict__ be1, const float* __restrict__ b2,
    const float* __restrict__ g2, const float* __restrict__ be2,
    float* __restrict__ s2, float* __restrict__ c2,
    float* __restrict__ s3, float* __restrict__ t3) {
  int t = threadIdx.x;
  if (t < 128) {
    float a = 0.f, b = 0.f;
    for (int k = 0; k < 128; ++k) {
      float w = W2[k * 128 + t];
      a += g1[k] * w; b += be1[k] * w;
    }
    s2[t] = a; c2[t] = b + b2[t];
  } else if (t < 192) {
    int n = t - 128;
    float a = 0.f, b = 0.f;
    for (int k = 0; k < 128; ++k) {
      float w = W3[k * 64 + n];
      a += g2[k] * w; b += be2[k] * w;
    }
    s3[n] = a; t3[n] = b;
  }
}

// ---------------- main triplet kernel ----------------
// 256 thr = 4 waves (wm:2 hidden-halves x wn:2 trip-halves), 64 triplets/block.
// GEMM1/2 transposed (lane-local LN stats); GEMM1 B-frags gathered from global
// ebf into regs (no X tile); GEMM3 un-transposed -> coalesced atomics.

__global__ __launch_bounds__(256, 5) void k_triplet(
    const u16* __restrict__ ebf, const int* __restrict__ tidx,
    const float* __restrict__ geo,
    const u16* __restrict__ wt1, const u16* __restrict__ wt2, const u16* __restrict__ wp3,
    const float* __restrict__ b1,
    const float* __restrict__ s2v, const float* __restrict__ c2v,
    const float* __restrict__ s3v,
    float* __restrict__ psum, float* __restrict__ cnt) {
  __shared__ __align__(16) char smem[LDS_TOTAL];
  float* P1S = (float*)(smem + LDS_P1S);
  float* P1Q = (float*)(smem + LDS_P1Q);
  float* P2S = (float*)(smem + LDS_P2S);
  float* P2Q = (float*)(smem + LDS_P2Q);
  int* EIJ = (int*)(smem + LDS_EIJ);

  const int tid = threadIdx.x;
  const int wave = tid >> 6, lane = tid & 63;
  const int wm = wave >> 1, wn = wave & 1;
  const int l15 = lane & 15, lg = lane >> 4;
  const int t0 = blockIdx.x * 64;

  // per-lane trips for the two B-fragment columns (f=0,1)
  const int tA = wn * 32 + l15;
  const int tB = tA + 16;
  int2 pA = ((const int2*)tidx)[t0 + tA];
  int2 pB = ((const int2*)tidx)[t0 + tB];

  // deep-prefetch 8 global B-frag gathers (16B each) for GEMM1 (k<128 part)
  const short8* eb = (const short8*)ebf;  // edge row = 8 x short8
  short8 bxA0 = eb[(size_t)pA.x * 8 + lg];
  short8 bxA1 = eb[(size_t)pA.x * 8 + 4 + lg];
  short8 bxA2 = eb[(size_t)pA.y * 8 + lg];
  short8 bxA3 = eb[(size_t)pA.y * 8 + 4 + lg];
  short8 bxB0 = eb[(size_t)pB.x * 8 + lg];
  short8 bxB1 = eb[(size_t)pB.x * 8 + 4 + lg];
  short8 bxB2 = eb[(size_t)pB.y * 8 + lg];
  short8 bxB3 = eb[(size_t)pB.y * 8 + 4 + lg];

  // stage EIJ + geo tail ([64][64B], swizzle (r&3)<<4)
  if (tid < 64) {
    int2 p = ((const int2*)tidx)[t0 + tid];
    EIJ[tid] = p.x;
    atomicAdd(&cnt[p.x], 1.0f);
    float4 gq = ((const float4*)geo)[t0 + tid];
    uint2 gw; gw.x = pkbf(gq.x, gq.y); gw.y = pkbf(gq.z, gq.w);
    char* tp = smem + LDS_TAIL + tid * 64;
    const int ts = (tid & 3) << 4;
    *(uint2*)(tp + (0 ^ ts)) = gw;
    *(uint2*)(tp + (0 ^ ts) + 8) = (uint2){0, 0};
    *(uint4*)(tp + (16 ^ ts)) = (uint4){0, 0, 0, 0};
    *(uint4*)(tp + (32 ^ ts)) = (uint4){0, 0, 0, 0};
    *(uint4*)(tp + (48 ^ ts)) = (uint4){0, 0, 0, 0};
  }
  __syncthreads();

  short8 btA = *(const short8*)(smem + LDS_TAIL + tA * 64 + ((lg * 16) ^ ((tA & 3) << 4)));
  short8 btB = *(const short8*)(smem + LDS_TAIL + tB * 64 + ((lg * 16) ^ ((tB & 3) << 4)));

  // ---- GEMM1: C1' = W1^T x X^T  (K=160) ----
  f32x4 acc[4][2];
#pragma unroll
  for (int mf = 0; mf < 4; ++mf) { acc[mf][0] = (f32x4)0.f; acc[mf][1] = (f32x4)0.f; }
  const short8* w1p = (const short8*)wt1;
#pragma unroll
  for (int s5 = 0; s5 < 5; ++s5) {
    short8 b0, b1x;
    if (s5 == 0) { b0 = bxA0; b1x = bxB0; }
    else if (s5 == 1) { b0 = bxA1; b1x = bxB1; }
    else if (s5 == 2) { b0 = bxA2; b1x = bxB2; }
    else if (s5 == 3) { b0 = bxA3; b1x = bxB3; }
    else { b0 = btA; b1x = btB; }
#pragma unroll
    for (int mf = 0; mf < 4; ++mf) {
      short8 aw = w1p[(wm * 64 + mf * 16 + l15) * 20 + s5 * 4 + lg];
      acc[mf][0] = MFMA16(aw, b0, acc[mf][0]);
      acc[mf][1] = MFMA16(aw, b1x, acc[mf][1]);
    }
  }

  // epilogue1: bias+silu; lane-local stats; write H^T [trip][n] bf16
  {
    float4 b1f[4];
#pragma unroll
    for (int mf = 0; mf < 4; ++mf)
      b1f[mf] = *(const float4*)(b1 + wm * 64 + mf * 16 + lg * 4);
    float st[2] = {0.f, 0.f}, sq[2] = {0.f, 0.f};
#pragma unroll
    for (int mf = 0; mf < 4; ++mf)
#pragma unroll
      for (int f = 0; f < 2; ++f)
#pragma unroll
        for (int q = 0; q < 4; ++q) {
          float v = silu(acc[mf][f][q] + b1f[mf][q]);
          acc[mf][f][q] = v;
          st[f] += v; sq[f] += v * v;
        }
#pragma unroll
    for (int f = 0; f < 2; ++f) {
      st[f] += __shfl_xor(st[f], 16); sq[f] += __shfl_xor(sq[f], 16);
      st[f] += __shfl_xor(st[f], 32); sq[f] += __shfl_xor(sq[f], 32);
    }
    if (lg == 0) {
#pragma unroll
      for (int f = 0; f < 2; ++f) {
        int trip = wn * 32 + f * 16 + l15;
        P1S[trip * 2 + wm] = st[f];
        P1Q[trip * 2 + wm] = sq[f];
      }
    }
#pragma unroll
    for (int mf = 0; mf < 4; ++mf)
#pragma unroll
      for (int f = 0; f < 2; ++f) {
        int trip = wn * 32 + f * 16 + l15;
        uint2 w;
        w.x = pkbf(acc[mf][f][0], acc[mf][f][1]);
        w.y = pkbf(acc[mf][f][2], acc[mf][f][3]);
        *(uint2*)(smem + LDS_HM + trip * 256 +
                  ((wm * 128 + mf * 32 + lg * 8) ^ ((trip & 7) << 4))) = w;
      }
  }
  __syncthreads();

  // ---- GEMM2: C2' = W2'^T x H^T  (K=128) ----
#pragma unroll
  for (int mf = 0; mf < 4; ++mf) { acc[mf][0] = (f32x4)0.f; acc[mf][1] = (f32x4)0.f; }
  const short8* w2p = (const short8*)wt2;
#pragma unroll
  for (int s4 = 0; s4 < 4; ++s4) {
    short8 bx0, bx1;
    {
      int trip = wn * 32 + l15;
      bx0 = *(const short8*)(smem + LDS_HM + trip * 256 +
                             ((s4 * 64 + lg * 16) ^ ((trip & 7) << 4)));
      int trip2 = trip + 16;
      bx1 = *(const short8*)(smem + LDS_HM + trip2 * 256 +
                             ((s4 * 64 + lg * 16) ^ ((trip2 & 7) << 4)));
    }
#pragma unroll
    for (int mf = 0; mf < 4; ++mf) {
      short8 aw = w2p[(wm * 64 + mf * 16 + l15) * 16 + s4 * 4 + lg];
      acc[mf][0] = MFMA16(aw, bx0, acc[mf][0]);
      acc[mf][1] = MFMA16(aw, bx1, acc[mf][1]);
    }
  }

  // epilogue2: folded LN1 + silu; stats into P2
  {
    float4 s2f[4], c2f[4];
#pragma unroll
    for (int mf = 0; mf < 4; ++mf) {
      s2f[mf] = *(const float4*)(s2v + wm * 64 + mf * 16 + lg * 4);
      c2f[mf] = *(const float4*)(c2v + wm * 64 + mf * 16 + lg * 4);
    }
    float mu[2], inv[2];
#pragma unroll
    for (int f = 0; f < 2; ++f) {
      int trip = wn * 32 + f * 16 + l15;
      float sm = P1S[trip * 2] + P1S[trip * 2 + 1];
      float qq = P1Q[trip * 2] + P1Q[trip * 2 + 1];
      mu[f] = sm * 0.0078125f;
      inv[f] = rsqrtf(fmaxf(qq * 0.0078125f - mu[f] * mu[f], 0.f) + 1e-5f);
    }
    float st[2] = {0.f, 0.f}, sq[2] = {0.f, 0.f};
#pragma unroll
    for (int mf = 0; mf < 4; ++mf)
#pragma unroll
      for (int f = 0; f < 2; ++f)
#pragma unroll
        for (int q = 0; q < 4; ++q) {
          float y = inv[f] * (acc[mf][f][q] - mu[f] * s2f[mf][q]) + c2f[mf][q];
          float v = silu(y);
          acc[mf][f][q] = v;
          st[f] += v; sq[f] += v * v;
        }
#pragma unroll
    for (int f = 0; f < 2; ++f) {
      st[f] += __shfl_xor(st[f], 16); sq[f] += __shfl_xor(sq[f], 16);
      st[f] += __shfl_xor(st[f], 32); sq[f] += __shfl_xor(sq[f], 32);
    }
    if (lg == 0) {
#pragma unroll
      for (int f = 0; f < 2; ++f) {
        int trip = wn * 32 + f * 16 + l15;
        P2S[trip * 2 + wm] = st[f];
        P2Q[trip * 2 + wm] = sq[f];
      }
    }
  }
  __syncthreads();  // all GEMM2 H-reads done; P2 visible

  // write M [trip][n] bf16 into HM region (aliases H)
#pragma unroll
  for (int mf = 0; mf < 4; ++mf)
#pragma unroll
    for (int f = 0; f < 2; ++f) {
      int trip = wn * 32 + f * 16 + l15;
      uint2 w;
      w.x = pkbf(acc[mf][f][0], acc[mf][f][1]);
      w.y = pkbf(acc[mf][f][2], acc[mf][f][3]);
      *(uint2*)(smem + LDS_HM + trip * 256 +
                ((wm * 128 + mf * 32 + lg * 8) ^ ((trip & 7) << 4))) = w;
    }
  __syncthreads();  // M visible

  // ---- GEMM3 (un-transposed): C3 = M x W3'  (K=128, N=64) ----
  f32x4 acc3[4];
#pragma unroll
  for (int nf = 0; nf < 4; ++nf) acc3[nf] = (f32x4)0.f;
  const short8* wb3 = (const short8*)wp3;
#pragma unroll
  for (int s4 = 0; s4 < 4; ++s4) {
    int row = wave * 16 + l15;
    short8 a = *(const short8*)(smem + LDS_HM + row * 256 +
                                ((s4 * 64 + lg * 16) ^ ((row & 7) << 4)));
#pragma unroll
    for (int nf = 0; nf < 4; ++nf) {
      short8 b = wb3[(s4 * 4 + lg) * 64 + nf * 16 + l15];
      acc3[nf] = MFMA16(a, b, acc3[nf]);
    }
  }
  {
    float s3c[4];
#pragma unroll
    for (int nf = 0; nf < 4; ++nf) s3c[nf] = s3v[nf * 16 + l15];
#pragma unroll
    for (int q = 0; q < 4; ++q) {
      int row = wave * 16 + lg * 4 + q;
      float sm = P2S[row * 2] + P2S[row * 2 + 1];
      float qq = P2Q[row * 2] + P2Q[row * 2 + 1];
      float mu = sm * 0.0078125f;
      float inv = rsqrtf(fmaxf(qq * 0.0078125f - mu * mu, 0.f) + 1e-5f);
      float* base = psum + (size_t)EIJ[row] * 64;
#pragma unroll
      for (int nf = 0; nf < 4; ++nf) {
        float y = inv * (acc3[nf][q] - mu * s3c[nf]);
        atomicAdd(base + nf * 16 + l15, y);
      }
    }
  }
}

// ---------------- finalize ----------------
// out = LN(ef + psum/max(cnt,1) + b3 + (cnt>0 ? t3 : 0), gn, bn)

__global__ __launch_bounds__(256) void k_final(
    const float* __restrict__ psum, const float* __restrict__ cnt,
    const float* __restrict__ ef, const float* __restrict__ b3,
    const float* __restrict__ t3, const float* __restrict__ gn,
    const float* __restrict__ bn, float* __restrict__ out) {
  int g = blockIdx.x * 256 + threadIdx.x;  // 4e6 threads, 4 lanes/edge
  int e = g >> 2, s = g & 3;
  float cv = cnt[e];
  float ic = 1.0f / fmaxf(cv, 1.0f);
  float tw = (cv > 0.f) ? 1.0f : 0.0f;
  float x[16];
  const float4* ps = (const float4*)(psum + (size_t)e * 64 + s * 16);
  const float4* fe = (const float4*)(ef + (size_t)e * 64 + s * 16);
  const float4* p3 = (const float4*)(b3 + s * 16);
  const float4* pt = (const float4*)(t3 + s * 16);
#pragma unroll
  for (int i = 0; i < 4; ++i) {
    float4 a = ps[i], b = fe[i], c = p3[i], d = pt[i];
    x[4 * i + 0] = b.x + a.x * ic + c.x + tw * d.x;
    x[4 * i + 1] = b.y + a.y * ic + c.y + tw * d.y;
    x[4 * i + 2] = b.z + a.z * ic + c.z + tw * d.z;
    x[4 * i + 3] = b.w + a.w * ic + c.w + tw * d.w;
  }
  float sum = 0.f, ss = 0.f;
#pragma unroll
  for (int i = 0; i < 16; ++i) { sum += x[i]; ss += x[i] * x[i]; }
  sum += __shfl_xor(sum, 1); ss += __shfl_xor(ss, 1);
  sum += __shfl_xor(sum, 2); ss += __shfl_xor(ss, 2);
  float mu = sum * (1.0f / 64.0f);
  float inv = rsqrtf(ss * (1.0f / 64.0f) - mu * mu + 1e-5f);
  float4* po = (float4*)(out + (size_t)e * 64 + s * 16);
#pragma unroll
  for (int i = 0; i < 4; ++i) {
    float4 gv = ((const float4*)(gn + s * 16))[i];
    float4 bv = ((const float4*)(bn + s * 16))[i];
    float4 o;
    o.x = (x[4 * i + 0] - mu) * inv * gv.x + bv.x;
    o.y = (x[4 * i + 1] - mu) * inv * gv.y + bv.y;
    o.z = (x[4 * i + 2] - mu) * inv * gv.z + bv.z;
    o.w = (x[4 * i + 3] - mu) * inv * gv.w + bv.w;
    po[i] = o;
  }
}

extern "C" void kernel_launch(void* const* d_in, const int* in_sizes, int n_in,
                              void* d_out, int out_size, void* d_ws, size_t ws_size,
                              hipStream_t stream) {
  const float* edge_feat = (const float*)d_in[0];
  const int* tidx = (const int*)d_in[1];
  const float* geo = (const float*)d_in[2];
  const float* W1 = (const float*)d_in[3];
  const float* b1 = (const float*)d_in[4];
  const float* g1 = (const float*)d_in[5];
  const float* be1 = (const float*)d_in[6];
  const float* W2 = (const float*)d_in[7];
  const float* b2 = (const float*)d_in[8];
  const float* g2 = (const float*)d_in[9];
  const float* be2 = (const float*)d_in[10];
  const float* W3 = (const float*)d_in[11];
  const float* b3 = (const float*)d_in[12];
  const float* gn = (const float*)d_in[13];
  const float* bn = (const float*)d_in[14];

  char* ws = (char*)d_ws;
  float* psum = (float*)(ws + OFF_PSUM);
  float* cnt = (float*)(ws + OFF_CNT);
  u16* ebf = (u16*)(ws + OFF_EBF);
  u16* wt1 = (u16*)(ws + OFF_WT1);
  u16* wt2 = (u16*)(ws + OFF_WT2);
  u16* wp3 = (u16*)(ws + OFF_WP3);
  float* s2 = (float*)(ws + OFF_S2);
  float* c2 = (float*)(ws + OFF_C2);
  float* s3 = (float*)(ws + OFF_S3);
  float* t3 = (float*)(ws + OFF_T3);
  float* out = (float*)d_out;

  hipMemsetAsync(ws, 0, 260000000ULL, stream);  // psum + cnt
  k_conv_edge<<<62500, 256, 0, stream>>>(edge_feat, ebf);
  k_pack_w<<<176, 256, 0, stream>>>(W1, W2, W3, g1, g2, wt1, wt2, wp3);
  k_pack_vec<<<1, 256, 0, stream>>>(W2, W3, g1, be1, b2, g2, be2, s2, c2, s3, t3);

  k_triplet<<<31250, 256, 0, stream>>>(ebf, tidx, geo, wt1, wt2, wp3,
                                       b1, s2, c2, s3, psum, cnt);
  k_final<<<15625, 256, 0, stream>>>(psum, cnt, edge_feat, b3, t3, gn, bn, out);
}